// Round 6
// baseline (49.042 us; speedup 1.0000x reference)
//
#include <hip/hip_runtime.h>
#include <math.h>

#define M_GT 128
#define NLEV 5
#define KCAND 135   // 5 levels * 27
#define TOPK_LOC 9
#define GX 186      // focal x-blocks: 96+48+24+12+6 (256 anchors each, level-pure)
#define GXW (GX*4)  // per-wave partials per sample

__device__ __forceinline__ float waveReduceSumF(float v) {
    #pragma unroll
    for (int off = 32; off > 0; off >>= 1)
        v += __shfl_xor(v, off, 64);
    return v;
}
// reduce within each 32-lane half-group
__device__ __forceinline__ float group32ReduceSumF(float v) {
    #pragma unroll
    for (int off = 16; off > 0; off >>= 1)
        v += __shfl_xor(v, off, 64);
    return v;
}

// One wave per (b, m) pair; 4 pairs per 256-thread block.
// Writes per (b, level, m): float4 {gs, ge, thresh, window_lo(bitcast int)}.
__global__ __launch_bounds__(256) void atss_summary_kernel(
    const float* __restrict__ ann,   // [B, 128, 3]
    const float* __restrict__ a0,
    const float* __restrict__ a1,
    const float* __restrict__ a2,
    const float* __restrict__ a3,
    const float* __restrict__ a4,
    float4* __restrict__ rec)        // [B][NLEV][M_GT]
{
    const int Llev[NLEV] = {8192, 4096, 2048, 1024, 512};
    const float* aptr[NLEV] = {a0, a1, a2, a3, a4};

    int wid  = threadIdx.x >> 6;
    int lane = threadIdx.x & 63;
    int pair = blockIdx.x*4 + wid;
    int b = pair >> 7, m = pair & 127;
    const float* g = ann + ((size_t)b*M_GT + m)*3;
    float gs = g[0], ge = g[1];
    float gc = (gs + ge)*0.5f;
    float glen = ge - gs;

    // Per level: contiguous window of the 9 nearest locations.
    // Centers (j+0.5)*s are exact f32 (s = power of two); same-side distances
    // strictly ordered; cross-side tie -> lower index (matches lax.top_k).
    int lo_arr[NLEV];
    #pragma unroll
    for (int l = 0; l < NLEV; ++l) {
        int L = Llev[l];
        float s = 65536.0f / (float)L;
        int j0 = (int)floorf(gc / s);
        if (j0 < 0) j0 = 0;
        if (j0 > L-1) j0 = L-1;
        int best = j0;
        float bd = fabsf(((float)j0 + 0.5f)*s - gc);
        if (j0 > 0) {
            float d = fabsf(((float)j0 - 0.5f)*s - gc);
            if (d <= bd) { best = j0-1; bd = d; }
        }
        if (j0+1 < L) {
            float d = fabsf(((float)j0 + 1.5f)*s - gc);
            if (d < bd)  { best = j0+1; bd = d; }
        }
        int lo = best, hi = best+1;
        #pragma unroll
        for (int t = 1; t < TOPK_LOC; ++t) {
            float dl = (lo > 0) ? fabsf(((float)(lo-1) + 0.5f)*s - gc) : 3.4e38f;
            float dr = (hi < L) ? fabsf(((float)hi    + 0.5f)*s - gc) : 3.4e38f;
            if (dl <= dr) --lo; else ++hi;          // tie -> left (lower index)
        }
        lo_arr[l] = lo;
    }

    // 135 candidate IoUs spread over lanes -> mean + unbiased std -> thresh
    float iouv[3];
    int valid[3];
    float sum = 0.f;
    #pragma unroll
    for (int it = 0; it < 3; ++it) {
        int c = lane + it*64;
        valid[it] = 0; iouv[it] = 0.f;
        if (c < KCAND) {
            int lev = c / 27;
            int w   = c % 27;
            int loc = lo_arr[lev] + w/3;
            int sc  = w % 3;
            int lidx = loc*3 + sc;
            const float* ap = aptr[lev] + (size_t)lidx*2;
            float as_ = ap[0], ae_ = ap[1];
            float iw = fminf(ae_, ge) - fmaxf(as_, gs);
            iw = fmaxf(iw, 0.f);
            float ua = (ae_ - as_) + glen - iw;
            ua = fmaxf(ua, 1e-8f);
            float iou = iw / ua;
            iouv[it] = iou;
            valid[it] = 1;
            sum += iou;
        }
    }
    sum = waveReduceSumF(sum);
    float mean = sum / (float)KCAND;
    float s2 = 0.f;
    #pragma unroll
    for (int it = 0; it < 3; ++it)
        if (valid[it]) { float d = iouv[it] - mean; s2 += d*d; }
    s2 = waveReduceSumF(s2);
    float thresh = mean + sqrtf(s2 / (float)(KCAND - 1));  // ddof=1

    if (lane < NLEV) {
        int lo_sel = (lane == 0) ? lo_arr[0] :
                     (lane == 1) ? lo_arr[1] :
                     (lane == 2) ? lo_arr[2] :
                     (lane == 3) ? lo_arr[3] : lo_arr[4];
        rec[((size_t)b*NLEV + lane)*M_GT + m] =
            make_float4(gs, ge, thresh, __int_as_float(lo_sel));
    }
}

// One block = 256 consecutive anchors of one level x NB samples.
// All cls loads issued up front (MLP); per-wave in-register ballot+popcount
// builds PACKED survivor records in LDS (one barrier, no atomics); uniform
// counted loop over broadcast LDS reads; per-wave partials (no 2nd barrier).
template<int NB>
__global__ __launch_bounds__(256) void focal_kernel(
    const float* __restrict__ cls,   // [B, A, C]
    const float4* __restrict__ rec,  // [B][NLEV][M_GT]
    const int* __restrict__ cidp,
    const float* __restrict__ a0,
    const float* __restrict__ a1,
    const float* __restrict__ a2,
    const float* __restrict__ a3,
    const float* __restrict__ a4,
    float2* __restrict__ parts,      // [B][GXW] {sum, count}
    int A, int C)
{
    int xb = blockIdx.x;
    int b0 = blockIdx.y * NB;
    int lev, lstart;
    if      (xb <  96) { lev = 0; lstart = 0;   }
    else if (xb < 144) { lev = 1; lstart = 96;  }
    else if (xb < 168) { lev = 2; lstart = 144; }
    else if (xb < 180) { lev = 3; lstart = 168; }
    else               { lev = 4; lstart = 180; }
    const float* ap = (lev==0)?a0:(lev==1)?a1:(lev==2)?a2:(lev==3)?a3:a4;
    int gb = (lev==0)?0:(lev==1)?24576:(lev==2)?36864:(lev==3)?43008:46080;

    int a0l  = (xb - lstart) * 256;  // level-local anchor offset
    int tid  = threadIdx.x;
    int wid  = tid >> 6;
    int lane = tid & 63;
    int lidx = a0l + tid;
    int ga   = gb + lidx;            // global anchor index

    // ---- issue ALL global loads up front ----
    const float2 aa = ((const float2*)ap)[lidx];
    int cid = *cidp;
    bool c8 = (C == 8);
    float4 u[NB], vv[NB];
    if (c8) {
        #pragma unroll
        for (int bb = 0; bb < NB; ++bb) {
            const float4* p4 = (const float4*)(cls + ((size_t)(b0+bb)*A + ga)*C);
            u[bb]  = p4[0];
            vv[bb] = p4[1];
        }
    }

    // ---- stage packed survivor records, one barrier, no atomics ----
    __shared__ float4 spack[NB][M_GT];
    __shared__ int    scount[NB];
    int locLo = a0l / 3;
    int locHi = (a0l + 255) / 3;
    #pragma unroll
    for (int k = 0; k < NB; ++k) {
        if ((k & 3) == wid) {        // wave-uniform guard: whole wave enters
            const float4* rbase = rec + ((size_t)(b0+k)*NLEV + lev)*M_GT;
            float4 r0 = rbase[lane];
            float4 r1 = rbase[lane + 64];
            int lo0 = __float_as_int(r0.w), lo1 = __float_as_int(r1.w);
            bool ov0 = (lo0 <= locHi) && (lo0 + (TOPK_LOC-1) >= locLo);
            bool ov1 = (lo1 <= locHi) && (lo1 + (TOPK_LOC-1) >= locLo);
            unsigned long long mk0 = __ballot(ov0);
            unsigned long long mk1 = __ballot(ov1);
            unsigned long long below = ((unsigned long long)1 << lane) - 1;
            int s0 = __popcll(mk0 & below);
            int s1 = __popcll(mk0) + __popcll(mk1 & below);
            if (ov0) spack[k][s0] = r0;
            if (ov1) spack[k][s1] = r1;
            if (lane == 0) scount[k] = __popcll(mk0) + __popcll(mk1);
        }
    }
    __syncthreads();

    // ---- per-sample: positivity (uniform counted loop, broadcast LDS) ----
    float as_ = aa.x, ae_ = aa.y;
    float cx  = (as_ + ae_) * 0.5f;
    int  aloc = lidx / 3;
    float lsum[NB];
    int   myp[NB];
    #pragma unroll
    for (int bb = 0; bb < NB; ++bb) {
        int n = scount[bb];
        int p = 0;
        for (int i = 0; i < n; ++i) {
            float4 r = spack[bb][i];
            int lo = __float_as_int(r.w);
            if ((unsigned)(aloc - lo) < (unsigned)TOPK_LOC) {
                float gs = r.x, ge = r.y;
                float glen = ge - gs;
                float iw = fminf(ae_, ge) - fmaxf(as_, gs);
                iw = fmaxf(iw, 0.f);
                float ua = (ae_ - as_) + glen - iw;
                ua = fmaxf(ua, 1e-8f);
                float iou = iw / ua;
                if (iou >= r.z && fminf(cx - gs, ge - cx) > 0.01f) p = 1;
            }
        }
        myp[bb] = p;

        // focal sum over channels (branchless select)
        float l = 0.f;
        if (c8) {
            float x8[8] = {u[bb].x, u[bb].y, u[bb].z, u[bb].w,
                           vv[bb].x, vv[bb].y, vv[bb].z, vv[bb].w};
            #pragma unroll
            for (int c = 0; c < 8; ++c) {
                float x = fminf(fmaxf(x8[c], 1e-4f), 0.9999f);
                float q = 1.f - x;
                float neg = 0.75f * x*x * (-__logf(q));
                float pst = 0.25f * q*q * (-__logf(x));
                l += ((p != 0) && (c == cid)) ? pst : neg;
            }
        } else {
            const float* pp = cls + ((size_t)(b0+bb)*A + ga)*C;
            for (int c = 0; c < C; ++c) {
                float x = fminf(fmaxf(pp[c], 1e-4f), 0.9999f);
                float q = 1.f - x;
                float neg = 0.75f * x*x * (-__logf(q));
                float pst = 0.25f * q*q * (-__logf(x));
                l += ((p != 0) && (c == cid)) ? pst : neg;
            }
        }
        lsum[bb] = l;
    }

    // ---- per-wave partials (no barrier needed) ----
    #pragma unroll
    for (int bb = 0; bb < NB; ++bb) {
        float s = waveReduceSumF(lsum[bb]);
        float c = waveReduceSumF((float)myp[bb]);
        if (lane == 0)
            parts[(size_t)(b0+bb)*GXW + xb*4 + wid] = make_float2(s, c);
    }
}

// 256 threads: 32-lane group per sample (b = tid>>5, strided if B>8).
__global__ __launch_bounds__(256) void finalize_kernel(
    const float2* __restrict__ parts,
    float* __restrict__ out, int B)
{
    int tid = threadIdx.x;
    int grp = tid >> 5;
    int g0  = tid & 31;
    float tacc = 0.f;
    for (int b = grp; b < B; b += 8) {
        float s = 0.f, c = 0.f;
        for (int g = g0; g < GXW; g += 32) {
            float2 pc = parts[(size_t)b*GXW + g];
            s += pc.x; c += pc.y;
        }
        s = group32ReduceSumF(s);
        c = group32ReduceSumF(c);
        if (g0 == 0) tacc += s / fmaxf(c, 1.0f);
    }
    __shared__ float sh[8];
    if (g0 == 0) sh[grp] = tacc;
    __syncthreads();
    if (tid == 0) {
        float t = 0.f;
        #pragma unroll
        for (int i = 0; i < 8; ++i) t += sh[i];
        out[0] = t / (float)B;
    }
}

extern "C" void kernel_launch(void* const* d_in, const int* in_sizes, int n_in,
                              void* d_out, int out_size, void* d_ws, size_t ws_size,
                              hipStream_t stream)
{
    const float* cls = (const float*)d_in[0];
    const float* ann = (const float*)d_in[1];
    const int* cid;
    const float *a0, *a1, *a2, *a3, *a4;
    int ai;
    if (in_sizes[2] == 1) { cid = (const int*)d_in[2]; ai = 3; }
    else                  { cid = (const int*)d_in[7]; ai = 2; }
    a0 = (const float*)d_in[ai+0];
    a1 = (const float*)d_in[ai+1];
    a2 = (const float*)d_in[ai+2];
    a3 = (const float*)d_in[ai+3];
    a4 = (const float*)d_in[ai+4];

    int A = (in_sizes[ai] + in_sizes[ai+1] + in_sizes[ai+2] + in_sizes[ai+3] + in_sizes[ai+4]) / 2;
    int B = in_sizes[1] / (M_GT * 3);
    int C = (int)((long long)in_sizes[0] / ((long long)B * A));

    float4* rec  = (float4*)d_ws;                                  // [B][5][128]
    size_t recBytes = (size_t)B * NLEV * M_GT * sizeof(float4);
    size_t off1 = (recBytes + 255) & ~(size_t)255;
    float2* parts = (float2*)((char*)d_ws + off1);                 // [B][GXW]

    atss_summary_kernel<<<(B*M_GT + 3)/4, 256, 0, stream>>>(ann, a0, a1, a2, a3, a4, rec);

    if ((B & 7) == 0) {
        dim3 g2(GX, B/8);
        focal_kernel<8><<<g2, 256, 0, stream>>>(cls, rec, cid, a0, a1, a2, a3, a4,
                                                parts, A, C);
    } else {
        dim3 g2(GX, B);
        focal_kernel<1><<<g2, 256, 0, stream>>>(cls, rec, cid, a0, a1, a2, a3, a4,
                                                parts, A, C);
    }

    finalize_kernel<<<1, 256, 0, stream>>>(parts, (float*)d_out, B);
}

// Round 8
// 17.949 us; speedup vs baseline: 2.7322x; 2.7322x over previous
//
#include <hip/hip_runtime.h>
#include <math.h>

#define M_GT 128
#define NLEV 5
#define KCAND 135   // 5 levels * 27
#define TOPK_LOC 9
#define GX 186      // focal x-blocks: 96+48+24+12+6 (256 anchors each, level-pure)

__device__ __forceinline__ float waveReduceSumF(float v) {
    #pragma unroll
    for (int off = 32; off > 0; off >>= 1)
        v += __shfl_xor(v, off, 64);
    return v;
}
// reduce within each 32-lane half-group
__device__ __forceinline__ float group32ReduceSumF(float v) {
    #pragma unroll
    for (int off = 16; off > 0; off >>= 1)
        v += __shfl_xor(v, off, 64);
    return v;
}

// One wave per (b, m) pair; 4 pairs per 256-thread block.
// Computes the FULL ATSS decision here: per (b, level, m) writes
// int2 { start_global_anchor, mask27 } where mask bit w = anchor (start+w)
// is positive for this gt. (Candidate w of level l IS anchor 3*lo+w —
// 27 contiguous anchors — since lidx = 3*(lo+w/3) + w%3 = 3*lo + w.)
__global__ __launch_bounds__(256) void atss_summary_kernel(
    const float* __restrict__ ann,   // [B, 128, 3]
    const float* __restrict__ a0,
    const float* __restrict__ a1,
    const float* __restrict__ a2,
    const float* __restrict__ a3,
    const float* __restrict__ a4,
    int2* __restrict__ rec)          // [B][NLEV][M_GT]
{
    const int Llev[NLEV] = {8192, 4096, 2048, 1024, 512};
    const float* aptr[NLEV] = {a0, a1, a2, a3, a4};

    int wid  = threadIdx.x >> 6;
    int lane = threadIdx.x & 63;
    int pair = blockIdx.x*4 + wid;
    int b = pair >> 7, m = pair & 127;
    const float* g = ann + ((size_t)b*M_GT + m)*3;
    float gs = g[0], ge = g[1];
    float gc = (gs + ge)*0.5f;
    float glen = ge - gs;

    // Per level: contiguous window of the 9 nearest locations.
    // Centers (j+0.5)*s are exact f32 (s = power of two); same-side distances
    // strictly ordered; cross-side tie -> lower index (matches lax.top_k).
    int lo_arr[NLEV];
    #pragma unroll
    for (int l = 0; l < NLEV; ++l) {
        int L = Llev[l];
        float s = 65536.0f / (float)L;
        int j0 = (int)floorf(gc / s);
        if (j0 < 0) j0 = 0;
        if (j0 > L-1) j0 = L-1;
        int best = j0;
        float bd = fabsf(((float)j0 + 0.5f)*s - gc);
        if (j0 > 0) {
            float d = fabsf(((float)j0 - 0.5f)*s - gc);
            if (d <= bd) { best = j0-1; bd = d; }
        }
        if (j0+1 < L) {
            float d = fabsf(((float)j0 + 1.5f)*s - gc);
            if (d < bd)  { best = j0+1; bd = d; }
        }
        int lo = best, hi = best+1;
        #pragma unroll
        for (int t = 1; t < TOPK_LOC; ++t) {
            float dl = (lo > 0) ? fabsf(((float)(lo-1) + 0.5f)*s - gc) : 3.4e38f;
            float dr = (hi < L) ? fabsf(((float)hi    + 0.5f)*s - gc) : 3.4e38f;
            if (dl <= dr) --lo; else ++hi;          // tie -> left (lower index)
        }
        lo_arr[l] = lo;
    }

    // 135 candidate IoUs spread over lanes -> mean + unbiased std -> thresh
    float iouv[3], cxv[3];
    int valid[3];
    float sum = 0.f;
    #pragma unroll
    for (int it = 0; it < 3; ++it) {
        int c = lane + it*64;
        valid[it] = 0; iouv[it] = 0.f; cxv[it] = 0.f;
        if (c < KCAND) {
            int lev = c / 27;
            int w   = c % 27;
            int loc = lo_arr[lev] + w/3;
            int sc  = w % 3;
            int lidx = loc*3 + sc;
            const float* ap = aptr[lev] + (size_t)lidx*2;
            float as_ = ap[0], ae_ = ap[1];
            float iw = fminf(ae_, ge) - fmaxf(as_, gs);
            iw = fmaxf(iw, 0.f);
            float ua = (ae_ - as_) + glen - iw;
            ua = fmaxf(ua, 1e-8f);
            float iou = iw / ua;
            iouv[it] = iou;
            cxv[it]  = (as_ + ae_)*0.5f;
            valid[it] = 1;
            sum += iou;
        }
    }
    sum = waveReduceSumF(sum);
    float mean = sum / (float)KCAND;
    float s2 = 0.f;
    #pragma unroll
    for (int it = 0; it < 3; ++it)
        if (valid[it]) { float d = iouv[it] - mean; s2 += d*d; }
    s2 = waveReduceSumF(s2);
    float thresh = mean + sqrtf(s2 / (float)(KCAND - 1));  // ddof=1

    // per-candidate positivity -> 3 ballots (192 bits, wave-uniform)
    unsigned long long m0, m1, m2;
    {
        bool p0 = valid[0] && (iouv[0] >= thresh) &&
                  (fminf(cxv[0] - gs, ge - cxv[0]) > 0.01f);
        bool p1 = valid[1] && (iouv[1] >= thresh) &&
                  (fminf(cxv[1] - gs, ge - cxv[1]) > 0.01f);
        bool p2 = valid[2] && (iouv[2] >= thresh) &&
                  (fminf(cxv[2] - gs, ge - cxv[2]) > 0.01f);
        m0 = __ballot(p0);
        m1 = __ballot(p1);
        m2 = __ballot(p2);
    }

    // lane l < 5 extracts its level's 27 bits (c in [27l, 27l+27)) and writes
    if (lane < NLEV) {
        unsigned long long wlo = (lane < 3) ? m0 : m1;
        unsigned long long whi = (lane < 3) ? m1 : m2;
        int off = (27*lane) & 63;
        unsigned long long lp = wlo >> off;
        if (off + 27 > 64) lp |= (whi << (64 - off));
        unsigned int mask27 = (unsigned int)(lp & ((1u << 27) - 1));
        int lo_sel = (lane == 0) ? lo_arr[0] :
                     (lane == 1) ? lo_arr[1] :
                     (lane == 2) ? lo_arr[2] :
                     (lane == 3) ? lo_arr[3] : lo_arr[4];
        int gb = (lane == 0) ? 0 :
                 (lane == 1) ? 24576 :
                 (lane == 2) ? 36864 :
                 (lane == 3) ? 43008 : 46080;
        int start = gb + 3*lo_sel;       // global index of candidate anchor 0
        rec[((size_t)b*NLEV + lane)*M_GT + m] = make_int2(start, (int)mask27);
    }
}

// One block = 256 consecutive anchors of one level for one sample.
// Builds the block's 256-bit pos map from the int2 records via LDS atomicOr,
// then pure elementwise focal math. No fp recompute, no serial loops.
__global__ __launch_bounds__(256) void focal_kernel(
    const float* __restrict__ cls,   // [B, A, C]
    const int2* __restrict__ rec,    // [B][NLEV][M_GT]
    const int* __restrict__ cidp,
    float2* __restrict__ parts,      // [B][GX] {sum, count}
    int A, int C)
{
    int xb = blockIdx.x;
    int b  = blockIdx.y;
    int lev, lstart;
    if      (xb <  96) { lev = 0; lstart = 0;   }
    else if (xb < 144) { lev = 1; lstart = 96;  }
    else if (xb < 168) { lev = 2; lstart = 144; }
    else if (xb < 180) { lev = 3; lstart = 168; }
    else               { lev = 4; lstart = 180; }
    int gb = (lev==0)?0:(lev==1)?24576:(lev==2)?36864:(lev==3)?43008:46080;

    int tid = threadIdx.x;
    int ga  = gb + (xb - lstart)*256 + tid;   // this thread's global anchor
    int blkStart = gb + (xb - lstart)*256;    // block's first global anchor

    // ---- issue cls loads up front (latency overlaps pos-map build) ----
    const float* p = cls + ((size_t)b*A + ga)*C;
    float4 u, vv;
    bool c8 = (C == 8);
    if (c8) { u = ((const float4*)p)[0]; vv = ((const float4*)p)[1]; }
    int cid = *cidp;

    // ---- build 256-bit pos map ----
    __shared__ unsigned int posb[8];
    if (tid < 8) posb[tid] = 0u;
    __syncthreads();
    if (tid < M_GT) {
        int2 r = rec[((size_t)b*NLEV + lev)*M_GT + tid];
        unsigned int m27 = (unsigned int)r.y;
        int off = r.x - blkStart;             // window bit0 position in block
        // only off in (-27, 256) can intersect; also keeps shifts < 64 (the
        // R7 bug: hardware shifts are mod-64, far-left windows leaked bits)
        if (m27 && off > -(int)27 && off < 256) {
            unsigned long long val = m27;
            if (off < 0) { val >>= (-off); off = 0; }   // -off <= 26: defined
            if (val) {
                int w0 = off >> 5;
                int sh = off & 31;
                unsigned long long sv = val << sh;      // <= 58 bits
                unsigned int lo32 = (unsigned int)sv;
                unsigned int hi32 = (unsigned int)(sv >> 32);
                if (lo32) atomicOr(&posb[w0], lo32);
                if (hi32 && w0 + 1 < 8) atomicOr(&posb[w0+1], hi32);
            }
        }
    }
    __syncthreads();
    int myp = (posb[tid >> 5] >> (tid & 31)) & 1;

    // ---- focal sum over channels (branchless select) ----
    float local = 0.f;
    if (c8) {
        float x8[8] = {u.x, u.y, u.z, u.w, vv.x, vv.y, vv.z, vv.w};
        #pragma unroll
        for (int c = 0; c < 8; ++c) {
            float x = fminf(fmaxf(x8[c], 1e-4f), 0.9999f);
            float q = 1.f - x;
            float neg = 0.75f * x*x * (-__logf(q));
            float pst = 0.25f * q*q * (-__logf(x));
            local += ((myp != 0) && (c == cid)) ? pst : neg;
        }
    } else {
        for (int c = 0; c < C; ++c) {
            float x = fminf(fmaxf(p[c], 1e-4f), 0.9999f);
            float q = 1.f - x;
            float neg = 0.75f * x*x * (-__logf(q));
            float pst = 0.25f * q*q * (-__logf(x));
            local += ((myp != 0) && (c == cid)) ? pst : neg;
        }
    }

    // ---- block reduce -> one float2 partial ----
    local = waveReduceSumF(local);
    float cf = waveReduceSumF((float)myp);
    __shared__ float sred[4];
    __shared__ float cred[4];
    int wid = tid >> 6;
    if ((tid & 63) == 0) { sred[wid] = local; cred[wid] = cf; }
    __syncthreads();
    if (tid == 0) {
        float s = sred[0] + sred[1] + sred[2] + sred[3];
        float c = cred[0] + cred[1] + cred[2] + cred[3];
        parts[(size_t)b*GX + xb] = make_float2(s, c);
    }
}

// 256 threads: 32-lane group per sample (strided if B > 8).
__global__ __launch_bounds__(256) void finalize_kernel(
    const float2* __restrict__ parts,
    float* __restrict__ out, int B)
{
    int tid = threadIdx.x;
    int grp = tid >> 5;
    int g0  = tid & 31;
    float tacc = 0.f;
    for (int b = grp; b < B; b += 8) {
        float s = 0.f, c = 0.f;
        for (int g = g0; g < GX; g += 32) {
            float2 pc = parts[(size_t)b*GX + g];
            s += pc.x; c += pc.y;
        }
        s = group32ReduceSumF(s);
        c = group32ReduceSumF(c);
        if (g0 == 0) tacc += s / fmaxf(c, 1.0f);
    }
    __shared__ float sh[8];
    if (g0 == 0) sh[grp] = tacc;
    __syncthreads();
    if (tid == 0) {
        float t = 0.f;
        #pragma unroll
        for (int i = 0; i < 8; ++i) t += sh[i];
        out[0] = t / (float)B;
    }
}

extern "C" void kernel_launch(void* const* d_in, const int* in_sizes, int n_in,
                              void* d_out, int out_size, void* d_ws, size_t ws_size,
                              hipStream_t stream)
{
    const float* cls = (const float*)d_in[0];
    const float* ann = (const float*)d_in[1];
    const int* cid;
    const float *a0, *a1, *a2, *a3, *a4;
    int ai;
    if (in_sizes[2] == 1) { cid = (const int*)d_in[2]; ai = 3; }
    else                  { cid = (const int*)d_in[7]; ai = 2; }
    a0 = (const float*)d_in[ai+0];
    a1 = (const float*)d_in[ai+1];
    a2 = (const float*)d_in[ai+2];
    a3 = (const float*)d_in[ai+3];
    a4 = (const float*)d_in[ai+4];

    int A = (in_sizes[ai] + in_sizes[ai+1] + in_sizes[ai+2] + in_sizes[ai+3] + in_sizes[ai+4]) / 2;
    int B = in_sizes[1] / (M_GT * 3);
    int C = (int)((long long)in_sizes[0] / ((long long)B * A));

    int2* rec = (int2*)d_ws;                                       // [B][5][128] = 40KB
    size_t recBytes = (size_t)B * NLEV * M_GT * sizeof(int2);
    size_t off1 = (recBytes + 255) & ~(size_t)255;
    float2* parts = (float2*)((char*)d_ws + off1);                 // [B][GX]

    atss_summary_kernel<<<(B*M_GT + 3)/4, 256, 0, stream>>>(ann, a0, a1, a2, a3, a4, rec);

    dim3 g2(GX, B);
    focal_kernel<<<g2, 256, 0, stream>>>(cls, rec, cid, parts, A, C);

    finalize_kernel<<<1, 256, 0, stream>>>(parts, (float*)d_out, B);
}

// Round 9
// 16.603 us; speedup vs baseline: 2.9537x; 1.0811x over previous
//
#include <hip/hip_runtime.h>
#include <math.h>

#define M_GT 128
#define NLEV 5
#define KCAND 135   // 5 levels * 27
#define TOPK_LOC 9
#define GX 186      // focal x-blocks: 96+48+24+12+6 (256 anchors each, level-pure)
#define PADU64 32   // one accumulator per 256B line

__device__ __forceinline__ float waveReduceSumF(float v) {
    #pragma unroll
    for (int off = 32; off > 0; off >>= 1)
        v += __shfl_xor(v, off, 64);
    return v;
}

// One wave per (b, m) pair; 4 pairs per 256-thread block.
// Computes the FULL ATSS decision: per (b, level, m) writes
// int2 { start_global_anchor, mask27 }: bit w = anchor (start+w) positive.
// (Candidate w of level l IS anchor 3*lo+w — 27 contiguous anchors.)
// Block 0 also zeroes the atomic funnel lines used by focal.
__global__ __launch_bounds__(256) void atss_summary_kernel(
    const float* __restrict__ ann,   // [B, 128, 3]
    const float* __restrict__ a0,
    const float* __restrict__ a1,
    const float* __restrict__ a2,
    const float* __restrict__ a3,
    const float* __restrict__ a4,
    int2* __restrict__ rec,          // [B][NLEV][M_GT]
    unsigned long long* __restrict__ fun)  // 25 lines * PADU64
{
    if (blockIdx.x == 0 && threadIdx.x < 25)
        fun[(size_t)threadIdx.x * PADU64] = 0ULL;

    const int Llev[NLEV] = {8192, 4096, 2048, 1024, 512};
    const float* aptr[NLEV] = {a0, a1, a2, a3, a4};

    int wid  = threadIdx.x >> 6;
    int lane = threadIdx.x & 63;
    int pair = blockIdx.x*4 + wid;
    int b = pair >> 7, m = pair & 127;
    const float* g = ann + ((size_t)b*M_GT + m)*3;
    float gs = g[0], ge = g[1];
    float gc = (gs + ge)*0.5f;
    float glen = ge - gs;

    // Per level: contiguous window of the 9 nearest locations.
    // Centers (j+0.5)*s are exact f32 (s = power of two); same-side distances
    // strictly ordered; cross-side tie -> lower index (matches lax.top_k).
    int lo_arr[NLEV];
    #pragma unroll
    for (int l = 0; l < NLEV; ++l) {
        int L = Llev[l];
        float s = 65536.0f / (float)L;
        int j0 = (int)floorf(gc / s);
        if (j0 < 0) j0 = 0;
        if (j0 > L-1) j0 = L-1;
        int best = j0;
        float bd = fabsf(((float)j0 + 0.5f)*s - gc);
        if (j0 > 0) {
            float d = fabsf(((float)j0 - 0.5f)*s - gc);
            if (d <= bd) { best = j0-1; bd = d; }
        }
        if (j0+1 < L) {
            float d = fabsf(((float)j0 + 1.5f)*s - gc);
            if (d < bd)  { best = j0+1; bd = d; }
        }
        int lo = best, hi = best+1;
        #pragma unroll
        for (int t = 1; t < TOPK_LOC; ++t) {
            float dl = (lo > 0) ? fabsf(((float)(lo-1) + 0.5f)*s - gc) : 3.4e38f;
            float dr = (hi < L) ? fabsf(((float)hi    + 0.5f)*s - gc) : 3.4e38f;
            if (dl <= dr) --lo; else ++hi;          // tie -> left (lower index)
        }
        lo_arr[l] = lo;
    }

    // 135 candidate IoUs spread over lanes -> mean + unbiased std -> thresh
    float iouv[3], cxv[3];
    int valid[3];
    float sum = 0.f;
    #pragma unroll
    for (int it = 0; it < 3; ++it) {
        int c = lane + it*64;
        valid[it] = 0; iouv[it] = 0.f; cxv[it] = 0.f;
        if (c < KCAND) {
            int lev = c / 27;
            int w   = c % 27;
            int loc = lo_arr[lev] + w/3;
            int sc  = w % 3;
            int lidx = loc*3 + sc;
            const float* ap = aptr[lev] + (size_t)lidx*2;
            float as_ = ap[0], ae_ = ap[1];
            float iw = fminf(ae_, ge) - fmaxf(as_, gs);
            iw = fmaxf(iw, 0.f);
            float ua = (ae_ - as_) + glen - iw;
            ua = fmaxf(ua, 1e-8f);
            float iou = iw / ua;
            iouv[it] = iou;
            cxv[it]  = (as_ + ae_)*0.5f;
            valid[it] = 1;
            sum += iou;
        }
    }
    sum = waveReduceSumF(sum);
    float mean = sum / (float)KCAND;
    float s2 = 0.f;
    #pragma unroll
    for (int it = 0; it < 3; ++it)
        if (valid[it]) { float d = iouv[it] - mean; s2 += d*d; }
    s2 = waveReduceSumF(s2);
    float thresh = mean + sqrtf(s2 / (float)(KCAND - 1));  // ddof=1

    // per-candidate positivity -> 3 ballots (192 bits, wave-uniform)
    unsigned long long m0, m1, m2;
    {
        bool p0 = valid[0] && (iouv[0] >= thresh) &&
                  (fminf(cxv[0] - gs, ge - cxv[0]) > 0.01f);
        bool p1 = valid[1] && (iouv[1] >= thresh) &&
                  (fminf(cxv[1] - gs, ge - cxv[1]) > 0.01f);
        bool p2 = valid[2] && (iouv[2] >= thresh) &&
                  (fminf(cxv[2] - gs, ge - cxv[2]) > 0.01f);
        m0 = __ballot(p0);
        m1 = __ballot(p1);
        m2 = __ballot(p2);
    }

    // lane l < 5 extracts its level's 27 bits (c in [27l, 27l+27)) and writes
    if (lane < NLEV) {
        unsigned long long wlo = (lane < 3) ? m0 : m1;
        unsigned long long whi = (lane < 3) ? m1 : m2;
        int off = (27*lane) & 63;
        unsigned long long lp = wlo >> off;
        if (off + 27 > 64) lp |= (whi << (64 - off));
        unsigned int mask27 = (unsigned int)(lp & ((1u << 27) - 1));
        int lo_sel = (lane == 0) ? lo_arr[0] :
                     (lane == 1) ? lo_arr[1] :
                     (lane == 2) ? lo_arr[2] :
                     (lane == 3) ? lo_arr[3] : lo_arr[4];
        int gb = (lane == 0) ? 0 :
                 (lane == 1) ? 24576 :
                 (lane == 2) ? 36864 :
                 (lane == 3) ? 43008 : 46080;
        int start = gb + 3*lo_sel;       // global index of candidate anchor 0
        rec[((size_t)b*NLEV + lane)*M_GT + m] = make_int2(start, (int)mask27);
    }
}

// One block = 256 consecutive anchors of one level for one sample.
// Pos map via LDS atomicOr from int2 records; elementwise focal; then a
// 3-level packed-u64 atomicAdd funnel replaces the finalize dispatch.
// All cross-block communication is through RMW return values: no fences,
// no global reads, bit-deterministic (integer adds are order-free).
//   level 1: acc[b*2 + (xb&1)]  [ticket:8 | fix = sum*2^16 : 40 | count:16]
//   level 2: sacc[b]            [ticket:8 | fix40 | count:16]
//   level 3: macc               [ticket:8 | term*2^24 : 56]
__global__ __launch_bounds__(256) void focal_kernel(
    const float* __restrict__ cls,   // [B, A, C]
    const int2* __restrict__ rec,    // [B][NLEV][M_GT]
    const int* __restrict__ cidp,
    unsigned long long* __restrict__ fun,  // 25 lines * PADU64
    float* __restrict__ out,
    int A, int C, int B)
{
    int xb = blockIdx.x;
    int b  = blockIdx.y;
    int lev, lstart;
    if      (xb <  96) { lev = 0; lstart = 0;   }
    else if (xb < 144) { lev = 1; lstart = 96;  }
    else if (xb < 168) { lev = 2; lstart = 144; }
    else if (xb < 180) { lev = 3; lstart = 168; }
    else               { lev = 4; lstart = 180; }
    int gb = (lev==0)?0:(lev==1)?24576:(lev==2)?36864:(lev==3)?43008:46080;

    int tid = threadIdx.x;
    int ga  = gb + (xb - lstart)*256 + tid;   // this thread's global anchor
    int blkStart = gb + (xb - lstart)*256;    // block's first global anchor

    // ---- issue cls loads up front (latency overlaps pos-map build) ----
    const float* p = cls + ((size_t)b*A + ga)*C;
    float4 u, vv;
    bool c8 = (C == 8);
    if (c8) { u = ((const float4*)p)[0]; vv = ((const float4*)p)[1]; }
    int cid = *cidp;

    // ---- build 256-bit pos map ----
    __shared__ unsigned int posb[8];
    if (tid < 8) posb[tid] = 0u;
    __syncthreads();
    if (tid < M_GT) {
        int2 r = rec[((size_t)b*NLEV + lev)*M_GT + tid];
        unsigned int m27 = (unsigned int)r.y;
        int off = r.x - blkStart;             // window bit0 position in block
        // only off in (-27, 256) can intersect; keeps shifts < 64 (HW mod-64)
        if (m27 && off > -27 && off < 256) {
            unsigned long long val = m27;
            if (off < 0) { val >>= (-off); off = 0; }   // -off <= 26: defined
            if (val) {
                int w0 = off >> 5;
                int sh = off & 31;
                unsigned long long sv = val << sh;      // <= 58 bits
                unsigned int lo32 = (unsigned int)sv;
                unsigned int hi32 = (unsigned int)(sv >> 32);
                if (lo32) atomicOr(&posb[w0], lo32);
                if (hi32 && w0 + 1 < 8) atomicOr(&posb[w0+1], hi32);
            }
        }
    }
    __syncthreads();
    int myp = (posb[tid >> 5] >> (tid & 31)) & 1;

    // ---- focal sum over channels (branchless select) ----
    float local = 0.f;
    if (c8) {
        float x8[8] = {u.x, u.y, u.z, u.w, vv.x, vv.y, vv.z, vv.w};
        #pragma unroll
        for (int c = 0; c < 8; ++c) {
            float x = fminf(fmaxf(x8[c], 1e-4f), 0.9999f);
            float q = 1.f - x;
            float neg = 0.75f * x*x * (-__logf(q));
            float pst = 0.25f * q*q * (-__logf(x));
            local += ((myp != 0) && (c == cid)) ? pst : neg;
        }
    } else {
        for (int c = 0; c < C; ++c) {
            float x = fminf(fmaxf(p[c], 1e-4f), 0.9999f);
            float q = 1.f - x;
            float neg = 0.75f * x*x * (-__logf(q));
            float pst = 0.25f * q*q * (-__logf(x));
            local += ((myp != 0) && (c == cid)) ? pst : neg;
        }
    }

    // ---- block reduce ----
    local = waveReduceSumF(local);
    float cf = waveReduceSumF((float)myp);
    __shared__ float sred[4];
    __shared__ float cred[4];
    int wid = tid >> 6;
    if ((tid & 63) == 0) { sred[wid] = local; cred[wid] = cf; }
    __syncthreads();
    if (tid != 0) return;

    float s = sred[0] + sred[1] + sred[2] + sred[3];
    float c = cred[0] + cred[1] + cred[2] + cred[3];

    // ---- level 1: half-sample line (<=93 adds/line, 16 lines parallel) ----
    unsigned long long fix = (unsigned long long)((double)s * 65536.0 + 0.5);
    unsigned long long cnt = (unsigned long long)(unsigned int)c;
    unsigned long long add1 = (1ULL << 56) | (fix << 16) | cnt;
    unsigned long long* accL = fun + (size_t)(b*2 + (xb & 1)) * PADU64;
    unsigned long long n1 = atomicAdd(accL, add1) + add1;
    if ((n1 >> 56) != 93ULL) return;          // not this line's completer

    // ---- level 2: sample line (2 adds) ----
    unsigned long long lfix = (n1 >> 16) & ((1ULL << 40) - 1);
    unsigned long long lcnt = n1 & 0xFFFFULL;
    unsigned long long add2 = (1ULL << 56) | (lfix << 16) | lcnt;
    unsigned long long* saccL = fun + (size_t)(16 + b) * PADU64;
    unsigned long long n2 = atomicAdd(saccL, add2) + add2;
    if ((n2 >> 56) != 2ULL) return;           // not this sample's completer

    // ---- level 3: master (B adds); completer writes the output ----
    unsigned long long sfix = (n2 >> 16) & ((1ULL << 40) - 1);
    unsigned long long scnt = n2 & 0xFFFFULL;
    double term = ((double)sfix / 65536.0) / (double)(scnt ? scnt : 1ULL);
    unsigned long long tfix = (unsigned long long)(term * 16777216.0 + 0.5);
    unsigned long long add3 = (1ULL << 56) | tfix;
    unsigned long long* maccL = fun + (size_t)24 * PADU64;
    unsigned long long n3 = atomicAdd(maccL, add3) + add3;
    if ((n3 >> 56) == (unsigned long long)B) {
        double total = (double)(n3 & ((1ULL << 56) - 1)) / 16777216.0;
        out[0] = (float)(total / (double)B);
    }
}

extern "C" void kernel_launch(void* const* d_in, const int* in_sizes, int n_in,
                              void* d_out, int out_size, void* d_ws, size_t ws_size,
                              hipStream_t stream)
{
    const float* cls = (const float*)d_in[0];
    const float* ann = (const float*)d_in[1];
    const int* cid;
    const float *a0, *a1, *a2, *a3, *a4;
    int ai;
    if (in_sizes[2] == 1) { cid = (const int*)d_in[2]; ai = 3; }
    else                  { cid = (const int*)d_in[7]; ai = 2; }
    a0 = (const float*)d_in[ai+0];
    a1 = (const float*)d_in[ai+1];
    a2 = (const float*)d_in[ai+2];
    a3 = (const float*)d_in[ai+3];
    a4 = (const float*)d_in[ai+4];

    int A = (in_sizes[ai] + in_sizes[ai+1] + in_sizes[ai+2] + in_sizes[ai+3] + in_sizes[ai+4]) / 2;
    int B = in_sizes[1] / (M_GT * 3);
    int C = (int)((long long)in_sizes[0] / ((long long)B * A));

    int2* rec = (int2*)d_ws;                                       // [B][5][128] = 40KB
    size_t recBytes = (size_t)B * NLEV * M_GT * sizeof(int2);
    size_t off1 = (recBytes + 255) & ~(size_t)255;
    unsigned long long* fun = (unsigned long long*)((char*)d_ws + off1);  // 25*256B

    atss_summary_kernel<<<(B*M_GT + 3)/4, 256, 0, stream>>>(ann, a0, a1, a2, a3, a4,
                                                            rec, fun);

    dim3 g2(GX, B);
    focal_kernel<<<g2, 256, 0, stream>>>(cls, rec, cid, fun, (float*)d_out, A, C, B);
}

// Round 10
// 16.170 us; speedup vs baseline: 3.0330x; 1.0268x over previous
//
#include <hip/hip_runtime.h>
#include <math.h>

#define M_GT 128
#define NLEV 5
#define KCAND 135   // 5 levels * 27
#define TOPK_LOC 9
#define NSB 62      // focal superblocks per sample: 3 tiles (768 anchors) each
#define PADU64 32   // one u64 accumulator per 256B line

__device__ __forceinline__ float waveReduceSumF(float v) {
    #pragma unroll
    for (int off = 32; off > 0; off >>= 1)
        v += __shfl_xor(v, off, 64);
    return v;
}

// One wave per (b, m) pair; 4 pairs per 256-thread block.
// Computes the FULL ATSS decision: per (b, level, m) writes
// int2 { start_global_anchor, mask27 }: bit w = anchor (start+w) positive.
// (Candidate w of level l IS anchor 3*lo+w — 27 contiguous anchors.)
// Block 0 also zeroes the 3B+1 atomic-funnel lines used by focal.
__global__ __launch_bounds__(256) void atss_summary_kernel(
    const float* __restrict__ ann,   // [B, 128, 3]
    const float* __restrict__ a0,
    const float* __restrict__ a1,
    const float* __restrict__ a2,
    const float* __restrict__ a3,
    const float* __restrict__ a4,
    int2* __restrict__ rec,          // [B][NLEV][M_GT]
    unsigned long long* __restrict__ fun,
    int B)
{
    if (blockIdx.x == 0 && threadIdx.x < (unsigned)(3*B + 1))
        fun[(size_t)threadIdx.x * PADU64] = 0ULL;

    const int Llev[NLEV] = {8192, 4096, 2048, 1024, 512};
    const float* aptr[NLEV] = {a0, a1, a2, a3, a4};

    int wid  = threadIdx.x >> 6;
    int lane = threadIdx.x & 63;
    int pair = blockIdx.x*4 + wid;
    int b = pair >> 7, m = pair & 127;
    const float* g = ann + ((size_t)b*M_GT + m)*3;
    float gs = g[0], ge = g[1];
    float gc = (gs + ge)*0.5f;
    float glen = ge - gs;

    // Per level: contiguous window of the 9 nearest locations.
    // Centers (j+0.5)*s are exact f32 (s = power of two); same-side distances
    // strictly ordered; cross-side tie -> lower index (matches lax.top_k).
    int lo_arr[NLEV];
    #pragma unroll
    for (int l = 0; l < NLEV; ++l) {
        int L = Llev[l];
        float s = 65536.0f / (float)L;
        int j0 = (int)floorf(gc / s);
        if (j0 < 0) j0 = 0;
        if (j0 > L-1) j0 = L-1;
        int best = j0;
        float bd = fabsf(((float)j0 + 0.5f)*s - gc);
        if (j0 > 0) {
            float d = fabsf(((float)j0 - 0.5f)*s - gc);
            if (d <= bd) { best = j0-1; bd = d; }
        }
        if (j0+1 < L) {
            float d = fabsf(((float)j0 + 1.5f)*s - gc);
            if (d < bd)  { best = j0+1; bd = d; }
        }
        int lo = best, hi = best+1;
        #pragma unroll
        for (int t = 1; t < TOPK_LOC; ++t) {
            float dl = (lo > 0) ? fabsf(((float)(lo-1) + 0.5f)*s - gc) : 3.4e38f;
            float dr = (hi < L) ? fabsf(((float)hi    + 0.5f)*s - gc) : 3.4e38f;
            if (dl <= dr) --lo; else ++hi;          // tie -> left (lower index)
        }
        lo_arr[l] = lo;
    }

    // 135 candidate IoUs spread over lanes -> mean + unbiased std -> thresh
    float iouv[3], cxv[3];
    int valid[3];
    float sum = 0.f;
    #pragma unroll
    for (int it = 0; it < 3; ++it) {
        int c = lane + it*64;
        valid[it] = 0; iouv[it] = 0.f; cxv[it] = 0.f;
        if (c < KCAND) {
            int lev = c / 27;
            int w   = c % 27;
            int loc = lo_arr[lev] + w/3;
            int sc  = w % 3;
            int lidx = loc*3 + sc;
            const float* ap = aptr[lev] + (size_t)lidx*2;
            float as_ = ap[0], ae_ = ap[1];
            float iw = fminf(ae_, ge) - fmaxf(as_, gs);
            iw = fmaxf(iw, 0.f);
            float ua = (ae_ - as_) + glen - iw;
            ua = fmaxf(ua, 1e-8f);
            float iou = iw / ua;
            iouv[it] = iou;
            cxv[it]  = (as_ + ae_)*0.5f;
            valid[it] = 1;
            sum += iou;
        }
    }
    sum = waveReduceSumF(sum);
    float mean = sum / (float)KCAND;
    float s2 = 0.f;
    #pragma unroll
    for (int it = 0; it < 3; ++it)
        if (valid[it]) { float d = iouv[it] - mean; s2 += d*d; }
    s2 = waveReduceSumF(s2);
    float thresh = mean + sqrtf(s2 / (float)(KCAND - 1));  // ddof=1

    // per-candidate positivity -> 3 ballots (192 bits, wave-uniform)
    unsigned long long m0, m1, m2;
    {
        bool p0 = valid[0] && (iouv[0] >= thresh) &&
                  (fminf(cxv[0] - gs, ge - cxv[0]) > 0.01f);
        bool p1 = valid[1] && (iouv[1] >= thresh) &&
                  (fminf(cxv[1] - gs, ge - cxv[1]) > 0.01f);
        bool p2 = valid[2] && (iouv[2] >= thresh) &&
                  (fminf(cxv[2] - gs, ge - cxv[2]) > 0.01f);
        m0 = __ballot(p0);
        m1 = __ballot(p1);
        m2 = __ballot(p2);
    }

    // lane l < 5 extracts its level's 27 bits (c in [27l, 27l+27)) and writes
    if (lane < NLEV) {
        unsigned long long wlo = (lane < 3) ? m0 : m1;
        unsigned long long whi = (lane < 3) ? m1 : m2;
        int off = (27*lane) & 63;
        unsigned long long lp = wlo >> off;
        if (off + 27 > 64) lp |= (whi << (64 - off));
        unsigned int mask27 = (unsigned int)(lp & ((1u << 27) - 1));
        int lo_sel = (lane == 0) ? lo_arr[0] :
                     (lane == 1) ? lo_arr[1] :
                     (lane == 2) ? lo_arr[2] :
                     (lane == 3) ? lo_arr[3] : lo_arr[4];
        int gb = (lane == 0) ? 0 :
                 (lane == 1) ? 24576 :
                 (lane == 2) ? 36864 :
                 (lane == 3) ? 43008 : 46080;
        int start = gb + 3*lo_sel;       // global index of candidate anchor 0
        rec[((size_t)b*NLEV + lane)*M_GT + m] = make_int2(start, (int)mask27);
    }
}

// One block = SUPERBLOCK of 768 consecutive anchors (3 tiles) of one level
// for one sample: 1 rec load + 1 barrier + 768-bit pos map, 6 float4 cls
// loads issued up front, 24 channel-terms/thread, 1 reduce, 1 funnel add.
// Funnel (packed u64, all info in RMW return values — no fences/reads):
//   level 1: fun[b*2+(sb&1)]  [ticket:8 | fix = sum*2^16 : 40 | count:16]  31 adds
//   level 2: fun[2B+b]        [ticket:8 | fix40 | count:16]                2 adds
//   level 3: fun[3B]          [ticket:8 | term*2^24 : 56]                  B adds
__global__ __launch_bounds__(256) void focal_kernel(
    const float* __restrict__ cls,   // [B, A, C]
    const int2* __restrict__ rec,    // [B][NLEV][M_GT]
    const int* __restrict__ cidp,
    unsigned long long* __restrict__ fun,
    float* __restrict__ out,
    int A, int C, int B)
{
    int sb = blockIdx.x;             // 0..61
    int b  = blockIdx.y;
    int lev, lsb;
    if      (sb < 32) { lev = 0; lsb = 0;  }
    else if (sb < 48) { lev = 1; lsb = 32; }
    else if (sb < 56) { lev = 2; lsb = 48; }
    else if (sb < 60) { lev = 3; lsb = 56; }
    else              { lev = 4; lsb = 60; }
    int gb = (lev==0)?0:(lev==1)?24576:(lev==2)?36864:(lev==3)?43008:46080;

    int tid = threadIdx.x;
    int sbStart = gb + (sb - lsb)*768;       // superblock's first global anchor

    // ---- issue ALL cls loads up front (latency overlaps pos-map build) ----
    bool c8 = (C == 8);
    float4 u0,v0,u1,v1,u2,v2;
    const float4* p4 = (const float4*)(cls + ((size_t)b*A + sbStart + tid)*(size_t)C);
    if (c8) {
        u0 = p4[0];    v0 = p4[1];           // anchor sbStart+tid
        u1 = p4[512];  v1 = p4[513];         // +256 anchors = +512 float4
        u2 = p4[1024]; v2 = p4[1025];        // +512 anchors
    }
    int cid = *cidp;

    // ---- build 768-bit pos map (24 words) ----
    __shared__ unsigned int posb[24];
    if (tid < 24) posb[tid] = 0u;
    __syncthreads();
    if (tid < M_GT) {
        int2 r = rec[((size_t)b*NLEV + lev)*M_GT + tid];
        unsigned int m27 = (unsigned int)r.y;
        int off = r.x - sbStart;             // window bit0 position in sblock
        // only off in (-27, 768) can intersect; keeps shifts < 64 (HW mod-64)
        if (m27 && off > -27 && off < 768) {
            unsigned long long val = m27;
            if (off < 0) { val >>= (-off); off = 0; }   // -off <= 26: defined
            if (val) {
                int w0 = off >> 5;
                int sh = off & 31;
                unsigned long long sv = val << sh;      // <= 58 bits
                unsigned int lo32 = (unsigned int)sv;
                unsigned int hi32 = (unsigned int)(sv >> 32);
                if (lo32) atomicOr(&posb[w0], lo32);
                if (hi32 && w0 + 1 < 24) atomicOr(&posb[w0+1], hi32);
            }
        }
    }
    __syncthreads();
    int w5 = tid >> 5, sh5 = tid & 31;
    int myp0 = (posb[w5]      >> sh5) & 1;
    int myp1 = (posb[w5 + 8]  >> sh5) & 1;
    int myp2 = (posb[w5 + 16] >> sh5) & 1;

    // ---- focal: 3 tiles x 8 channels per thread (branchless select) ----
    float local = 0.f;
    if (c8) {
        float x24[24] = {u0.x,u0.y,u0.z,u0.w, v0.x,v0.y,v0.z,v0.w,
                         u1.x,u1.y,u1.z,u1.w, v1.x,v1.y,v1.z,v1.w,
                         u2.x,u2.y,u2.z,u2.w, v2.x,v2.y,v2.z,v2.w};
        int mypv[3] = {myp0, myp1, myp2};
        #pragma unroll
        for (int t = 0; t < 3; ++t) {
            int mp = mypv[t];
            #pragma unroll
            for (int c = 0; c < 8; ++c) {
                float x = fminf(fmaxf(x24[t*8 + c], 1e-4f), 0.9999f);
                float q = 1.f - x;
                float neg = 0.75f * x*x * (-__logf(q));
                float pst = 0.25f * q*q * (-__logf(x));
                local += ((mp != 0) && (c == cid)) ? pst : neg;
            }
        }
    } else {
        int mypv[3] = {myp0, myp1, myp2};
        for (int t = 0; t < 3; ++t) {
            const float* pp = cls + ((size_t)b*A + sbStart + t*256 + tid)*(size_t)C;
            int mp = mypv[t];
            for (int c = 0; c < C; ++c) {
                float x = fminf(fmaxf(pp[c], 1e-4f), 0.9999f);
                float q = 1.f - x;
                float neg = 0.75f * x*x * (-__logf(q));
                float pst = 0.25f * q*q * (-__logf(x));
                local += ((mp != 0) && (c == cid)) ? pst : neg;
            }
        }
    }
    float cfl = (float)(myp0 + myp1 + myp2);

    // ---- block reduce (one pass over combined 3-tile values) ----
    local = waveReduceSumF(local);
    float cf = waveReduceSumF(cfl);
    __shared__ float sred[4];
    __shared__ float cred[4];
    int wid = tid >> 6;
    if ((tid & 63) == 0) { sred[wid] = local; cred[wid] = cf; }
    __syncthreads();
    if (tid != 0) return;

    float s = sred[0] + sred[1] + sred[2] + sred[3];
    float c = cred[0] + cred[1] + cred[2] + cred[3];

    // ---- level 1: half-sample line (31 adds/line, 2B lines parallel) ----
    unsigned long long fix = (unsigned long long)((double)s * 65536.0 + 0.5);
    unsigned long long cnt = (unsigned long long)(unsigned int)c;
    unsigned long long add1 = (1ULL << 56) | (fix << 16) | cnt;
    unsigned long long* accL = fun + (size_t)(b*2 + (sb & 1)) * PADU64;
    unsigned long long n1 = atomicAdd(accL, add1) + add1;
    if ((n1 >> 56) != (unsigned long long)(NSB/2)) return;   // not completer

    // ---- level 2: sample line (2 adds) ----
    unsigned long long lfix = (n1 >> 16) & ((1ULL << 40) - 1);
    unsigned long long lcnt = n1 & 0xFFFFULL;
    unsigned long long add2 = (1ULL << 56) | (lfix << 16) | lcnt;
    unsigned long long* saccL = fun + (size_t)(2*B + b) * PADU64;
    unsigned long long n2 = atomicAdd(saccL, add2) + add2;
    if ((n2 >> 56) != 2ULL) return;           // not this sample's completer

    // ---- level 3: master (B adds); completer writes the output ----
    unsigned long long sfix = (n2 >> 16) & ((1ULL << 40) - 1);
    unsigned long long scnt = n2 & 0xFFFFULL;
    double term = ((double)sfix / 65536.0) / (double)(scnt ? scnt : 1ULL);
    unsigned long long tfix = (unsigned long long)(term * 16777216.0 + 0.5);
    unsigned long long add3 = (1ULL << 56) | tfix;
    unsigned long long* maccL = fun + (size_t)(3*B) * PADU64;
    unsigned long long n3 = atomicAdd(maccL, add3) + add3;
    if ((n3 >> 56) == (unsigned long long)B) {
        double total = (double)(n3 & ((1ULL << 56) - 1)) / 16777216.0;
        out[0] = (float)(total / (double)B);
    }
}

extern "C" void kernel_launch(void* const* d_in, const int* in_sizes, int n_in,
                              void* d_out, int out_size, void* d_ws, size_t ws_size,
                              hipStream_t stream)
{
    const float* cls = (const float*)d_in[0];
    const float* ann = (const float*)d_in[1];
    const int* cid;
    const float *a0, *a1, *a2, *a3, *a4;
    int ai;
    if (in_sizes[2] == 1) { cid = (const int*)d_in[2]; ai = 3; }
    else                  { cid = (const int*)d_in[7]; ai = 2; }
    a0 = (const float*)d_in[ai+0];
    a1 = (const float*)d_in[ai+1];
    a2 = (const float*)d_in[ai+2];
    a3 = (const float*)d_in[ai+3];
    a4 = (const float*)d_in[ai+4];

    int A = (in_sizes[ai] + in_sizes[ai+1] + in_sizes[ai+2] + in_sizes[ai+3] + in_sizes[ai+4]) / 2;
    int B = in_sizes[1] / (M_GT * 3);
    int C = (int)((long long)in_sizes[0] / ((long long)B * A));

    int2* rec = (int2*)d_ws;                                       // [B][5][128] = 40KB
    size_t recBytes = (size_t)B * NLEV * M_GT * sizeof(int2);
    size_t off1 = (recBytes + 255) & ~(size_t)255;
    unsigned long long* fun = (unsigned long long*)((char*)d_ws + off1);

    atss_summary_kernel<<<(B*M_GT + 3)/4, 256, 0, stream>>>(ann, a0, a1, a2, a3, a4,
                                                            rec, fun, B);

    dim3 g2(NSB, B);
    focal_kernel<<<g2, 256, 0, stream>>>(cls, rec, cid, fun, (float*)d_out, A, C, B);
}